// Round 6
// baseline (231.278 us; speedup 1.0000x reference)
//
#include <hip/hip_runtime.h>

#define N_NODES 50000
#define N_EDGES 800000
#define IN_SIZE 128
#define HIDDEN 128
#define OUT_SIZE 64

#define CHUNKS 128
#define CHUNK_EDGES 6250      // 128 * 6250 = 800000 exactly
#define GEMMA_TILES 1563      // ceil(50000/32)
#define NBS 196               // ceil(50000/256) block sums, granularity 256 nodes

static __device__ inline unsigned pack_bf16x2(float a, float b) {
    unsigned ua = __float_as_uint(a);
    unsigned ub = __float_as_uint(b);
    unsigned ra = (ua + 0x7fffu + ((ua >> 16) & 1u)) >> 16;        // RNE
    unsigned rb = (ub + 0x7fffu + ((ub >> 16) & 1u)) & 0xffff0000u;
    return ra | rb;
}

static __device__ inline unsigned pack_f16x2(float a, float b) {
    _Float16 ha = (_Float16)a, hb = (_Float16)b;       // RNE converts
    unsigned short ua = __builtin_bit_cast(unsigned short, ha);
    unsigned short ub = __builtin_bit_cast(unsigned short, hb);
    return (unsigned)ua | ((unsigned)ub << 16);
}

static __device__ inline float2 unpack_f16x2(unsigned u) {
    _Float16 lo = __builtin_bit_cast(_Float16, (unsigned short)(u & 0xffffu));
    _Float16 hi = __builtin_bit_cast(_Float16, (unsigned short)(u >> 16));
    return make_float2((float)lo, (float)hi);
}

static __device__ inline float bf_lo(unsigned w) { return __uint_as_float(w << 16); }
static __device__ inline float bf_hi(unsigned w) { return __uint_as_float(w & 0xffff0000u); }

static __device__ inline int bperm_i(int idx, int v) {
    return __builtin_amdgcn_ds_bpermute(idx << 2, v);
}
static __device__ inline float bperm_f(int idx, float v) {
    return __int_as_float(__builtin_amdgcn_ds_bpermute(idx << 2, __float_as_int(v)));
}

// ---- chunked LDS histogram: per-chunk dst/src counts + within-chunk rank ----
__global__ __launch_bounds__(1024) void hist_kernel(const int* __restrict__ src,
                                                    const int* __restrict__ dst,
                                                    unsigned char* __restrict__ cntD,
                                                    unsigned char* __restrict__ cntS,
                                                    unsigned char* __restrict__ rp) {
    __shared__ unsigned hD[12500];   // 50000 8-bit counters (dst)
    __shared__ unsigned hS[12500];   // 50000 8-bit counters (src)
    const int t = threadIdx.x;
    const int c = blockIdx.x;

    for (int i = t; i < 12500; i += 1024) { hD[i] = 0u; hS[i] = 0u; }
    __syncthreads();

    const int base = c * CHUNK_EDGES;
    for (int i = t; i < CHUNK_EDGES; i += 1024) {
        int e = base + i;
        int d = dst[e];
        int s = src[e];
        unsigned shd = (unsigned)(d & 3) * 8u;
        unsigned old = atomicAdd(&hD[d >> 2], 1u << shd);
        rp[e] = (unsigned char)((old >> shd) & 0xffu);   // rank within chunk
        atomicAdd(&hS[s >> 2], 1u << ((unsigned)(s & 3) * 8u));
    }
    __syncthreads();

    unsigned* gD = (unsigned*)cntD + (size_t)c * 12500;
    unsigned* gS = (unsigned*)cntS + (size_t)c * 12500;
    for (int i = t; i < 12500; i += 1024) { gD[i] = hD[i]; gS[i] = hS[i]; }
}

// ---------------- GEMM-A (standalone, 256 thr, 32 KB LDS): t1 = bf16(h @ W1) ----------------
__global__ __launch_bounds__(256) void gemmA_kernel(const float* __restrict__ h,
                                                    const float* __restrict__ W1,
                                                    unsigned short* __restrict__ t1) {
    __shared__ float sA[32][128];
    __shared__ float sW[32][128];

    const int tile = blockIdx.x;
    const int t  = threadIdx.x;
    const int tx = t & 31;
    const int ty = t >> 5;
    const int n0 = tile * 32;

    for (int i = t; i < 1024; i += 256) {
        int n = i >> 5, c = i & 31;
        int gn = n0 + n;
        float4 v = make_float4(0.f, 0.f, 0.f, 0.f);
        if (gn < N_NODES) v = ((const float4*)(h + (size_t)gn * 128))[c];
        ((float4*)sA[n])[c] = v;
    }

    float4 acc[4];
    #pragma unroll
    for (int i = 0; i < 4; ++i) acc[i] = make_float4(0.f, 0.f, 0.f, 0.f);

    for (int kc = 0; kc < 4; ++kc) {
        __syncthreads();
        for (int i = t; i < 1024; i += 256) {
            int k = i >> 5, c = i & 31;
            ((float4*)sW[k])[c] = ((const float4*)(W1 + (size_t)(kc * 32 + k) * 128))[c];
        }
        __syncthreads();
        #pragma unroll 4
        for (int k4 = 0; k4 < 32; k4 += 4) {
            float a0[4], a1[4], a2[4], a3[4];
            *(float4*)a0 = *(const float4*)&sA[ty * 4 + 0][kc * 32 + k4];
            *(float4*)a1 = *(const float4*)&sA[ty * 4 + 1][kc * 32 + k4];
            *(float4*)a2 = *(const float4*)&sA[ty * 4 + 2][kc * 32 + k4];
            *(float4*)a3 = *(const float4*)&sA[ty * 4 + 3][kc * 32 + k4];
            #pragma unroll
            for (int kk = 0; kk < 4; ++kk) {
                float4 w = ((float4*)sW[k4 + kk])[tx];
                acc[0].x = fmaf(a0[kk], w.x, acc[0].x);
                acc[0].y = fmaf(a0[kk], w.y, acc[0].y);
                acc[0].z = fmaf(a0[kk], w.z, acc[0].z);
                acc[0].w = fmaf(a0[kk], w.w, acc[0].w);
                acc[1].x = fmaf(a1[kk], w.x, acc[1].x);
                acc[1].y = fmaf(a1[kk], w.y, acc[1].y);
                acc[1].z = fmaf(a1[kk], w.z, acc[1].z);
                acc[1].w = fmaf(a1[kk], w.w, acc[1].w);
                acc[2].x = fmaf(a2[kk], w.x, acc[2].x);
                acc[2].y = fmaf(a2[kk], w.y, acc[2].y);
                acc[2].z = fmaf(a2[kk], w.z, acc[2].z);
                acc[2].w = fmaf(a2[kk], w.w, acc[2].w);
                acc[3].x = fmaf(a3[kk], w.x, acc[3].x);
                acc[3].y = fmaf(a3[kk], w.y, acc[3].y);
                acc[3].z = fmaf(a3[kk], w.z, acc[3].z);
                acc[3].w = fmaf(a3[kk], w.w, acc[3].w);
            }
        }
    }

    #pragma unroll
    for (int ni = 0; ni < 4; ++ni) {
        int gn = n0 + ty * 4 + ni;
        if (gn < N_NODES) {
            uint2 p;
            p.x = pack_bf16x2(acc[ni].x, acc[ni].y);
            p.y = pack_bf16x2(acc[ni].z, acc[ni].w);
            ((uint2*)(t1 + (size_t)gn * 128))[tx] = p;
        }
    }
}

// ---- fused: per-node chunk prefix (in-place) + norms + block-level scan ----
__global__ __launch_bounds__(256) void deg_scan_kernel(unsigned char* __restrict__ cntD,
                                                       const unsigned char* __restrict__ cntS,
                                                       int* __restrict__ row_ptr,
                                                       int* __restrict__ bsum,
                                                       float* __restrict__ norm_out,
                                                       float* __restrict__ norm_in) {
    const int t = threadIdx.x, lane = t & 63, w = t >> 6;
    const int n = blockIdx.x * 256 + t;
    unsigned sumD = 0u, sumS = 0u;
    if (n < N_NODES) {
        #pragma unroll 4
        for (int c = 0; c < CHUNKS; ++c) {
            size_t idx = (size_t)c * 50000 + n;
            unsigned v = cntD[idx];
            cntD[idx] = (unsigned char)sumD;   // exclusive prefix (total deg < 256)
            sumD += v;
            sumS += cntS[idx];
        }
        norm_in[n]  = rsqrtf((float)(sumD ? sumD : 1u));
        norm_out[n] = rsqrtf((float)(sumS ? sumS : 1u));
    }
    __shared__ int wsum[4];
    int v = (n < N_NODES) ? (int)sumD : 0;
    int incl = v;
    #pragma unroll
    for (int d = 1; d < 64; d <<= 1) {
        int u = __shfl_up(incl, d, 64);
        if (lane >= d) incl += u;
    }
    if (lane == 63) wsum[w] = incl;
    __syncthreads();
    int woff = 0, total = 0;
    #pragma unroll
    for (int j = 0; j < 4; ++j) {
        int s = wsum[j];
        if (j < w) woff += s;
        total += s;
    }
    if (n < N_NODES) row_ptr[n] = woff + incl - v;
    if (t == 0) bsum[blockIdx.x] = total;
}

// ---- scan of 196 block sums (single wave, chunks with carry) ----
__global__ __launch_bounds__(64) void scan2_kernel(int* __restrict__ bsum,
                                                   int* __restrict__ row_ptr) {
    const int lane = threadIdx.x;
    int carry = 0;
    for (int base = 0; base < NBS; base += 64) {
        int t = base + lane;
        int v = (t < NBS) ? bsum[t] : 0;
        int incl = v;
        #pragma unroll
        for (int d = 1; d < 64; d <<= 1) {
            int u = __shfl_up(incl, d, 64);
            if (lane >= d) incl += u;
        }
        int excl = carry + incl - v;
        if (t < NBS) bsum[t] = excl;
        if (t == NBS - 1) row_ptr[N_NODES] = N_EDGES - excl;
        carry += __shfl(incl, 63, 64);
    }
}

// ---- atomic-free CSR placement: row_ptr + bsum + chunk prefix + rank ----
__global__ __launch_bounds__(256) void place_kernel(const int* __restrict__ src,
                                                    const int* __restrict__ dst,
                                                    const int* __restrict__ row_ptr,
                                                    const int* __restrict__ bsum,
                                                    const unsigned char* __restrict__ cntD,
                                                    const unsigned char* __restrict__ rp,
                                                    int* __restrict__ eidx) {
    int e = blockIdx.x * 256 + threadIdx.x;
    if (e < N_EDGES) {
        int d = dst[e];
        int c = e / CHUNK_EDGES;
        int pos = row_ptr[d] + bsum[d >> 8] + (int)cntD[(size_t)c * 50000 + d] + (int)rp[e];
        eidx[pos] = src[e];
    }
}

// ---------------- GEMM-B: t2 = fp16(h1p @ W2)  (N x 128 @ 128 x 64) ----------------
__global__ __launch_bounds__(256) void gemmB_kernel(const float* __restrict__ h1p,
                                                    const float* __restrict__ W2,
                                                    unsigned short* __restrict__ t2h) {
    __shared__ float sA[32][128];
    __shared__ float sW[128][64];
    const int t  = threadIdx.x;
    const int tx = t & 15;
    const int ty = t >> 4;
    const int n0 = blockIdx.x * 32;

    for (int i = t; i < 1024; i += 256) {
        int n = i >> 5, c = i & 31;
        int gn = n0 + n;
        float4 v = make_float4(0.f, 0.f, 0.f, 0.f);
        if (gn < N_NODES) v = ((const float4*)(h1p + (size_t)gn * 128))[c];
        ((float4*)sA[n])[c] = v;
    }
    for (int i = t; i < 2048; i += 256) {
        int k = i >> 4, c = i & 15;
        ((float4*)sW[k])[c] = ((const float4*)(W2 + (size_t)k * 64))[c];
    }
    __syncthreads();

    float4 a0 = make_float4(0.f, 0.f, 0.f, 0.f);
    float4 a1 = make_float4(0.f, 0.f, 0.f, 0.f);
    #pragma unroll 4
    for (int k4 = 0; k4 < 128; k4 += 4) {
        float x0[4], x1[4];
        *(float4*)x0 = *(const float4*)&sA[ty * 2 + 0][k4];
        *(float4*)x1 = *(const float4*)&sA[ty * 2 + 1][k4];
        #pragma unroll
        for (int kk = 0; kk < 4; ++kk) {
            float4 w = ((float4*)sW[k4 + kk])[tx];
            a0.x = fmaf(x0[kk], w.x, a0.x); a0.y = fmaf(x0[kk], w.y, a0.y);
            a0.z = fmaf(x0[kk], w.z, a0.z); a0.w = fmaf(x0[kk], w.w, a0.w);
            a1.x = fmaf(x1[kk], w.x, a1.x); a1.y = fmaf(x1[kk], w.y, a1.y);
            a1.z = fmaf(x1[kk], w.z, a1.z); a1.w = fmaf(x1[kk], w.w, a1.w);
        }
    }

    #pragma unroll
    for (int ni = 0; ni < 2; ++ni) {
        int gn = n0 + ty * 2 + ni;
        if (gn < N_NODES) {
            float4 a = ni ? a1 : a0;
            uint2 p;
            p.x = pack_f16x2(a.x, a.y);
            p.y = pack_f16x2(a.z, a.w);
            ((uint2*)(t2h + (size_t)gn * 64))[tx] = p;
        }
    }
}

// ---------------- pull aggregation, 128 bf16 feats: 4 edges per VMEM inst ----------------
// quarter = lane>>4 selects edge within group of 4; each lane loads uint4 = 8 bf16 feats.
// Edge index/norm broadcast via ds_bpermute (idx = k + quarter). Tail edges: clamp idx,
// zero the norm -> exact no-op. h1p[n] = relu(ni*sum norm_out[s]*t1[s] + b1)*no
__global__ __launch_bounds__(256) void pull128_kernel(const unsigned short* __restrict__ xb,
                                                      const int* __restrict__ row_ptr,
                                                      const int* __restrict__ bsum,
                                                      const int* __restrict__ eidx,
                                                      const float* __restrict__ b1,
                                                      const float* __restrict__ norm_in,
                                                      const float* __restrict__ norm_out,
                                                      float* __restrict__ out) {
    int node = blockIdx.x * 4 + (threadIdx.x >> 6);
    node = __builtin_amdgcn_readfirstlane(node);
    const int lane = threadIdx.x & 63;
    const int quarter = lane >> 4;
    const int fl = lane & 15;
    const int beg = __builtin_amdgcn_readfirstlane(row_ptr[node] + bsum[node >> 8]);
    const int end = __builtin_amdgcn_readfirstlane(row_ptr[node + 1] + bsum[(node + 1) >> 8]);

    float4 accA0 = make_float4(0.f, 0.f, 0.f, 0.f);
    float4 accB0 = make_float4(0.f, 0.f, 0.f, 0.f);
    float4 accA1 = make_float4(0.f, 0.f, 0.f, 0.f);
    float4 accB1 = make_float4(0.f, 0.f, 0.f, 0.f);

    for (int base = beg; base < end; base += 64) {
        const int cnt = min(64, end - base);
        const int cm1 = cnt - 1;
        int my_e = 0;
        float my_n = 0.f;
        if (lane < cnt) {
            my_e = eidx[base + lane];
            my_n = norm_out[my_e];
        }
        int k = 0;
        for (; k + 16 <= cnt; k += 16) {      // 4 full groups, 4 uint4 loads in flight
            int i0 = k + quarter, i1 = k + 4 + quarter, i2 = k + 8 + quarter, i3 = k + 12 + quarter;
            int s0 = bperm_i(i0, my_e);
            int s1 = bperm_i(i1, my_e);
            int s2 = bperm_i(i2, my_e);
            int s3 = bperm_i(i3, my_e);
            float n0 = bperm_f(i0, my_n);
            float n1 = bperm_f(i1, my_n);
            float n2 = bperm_f(i2, my_n);
            float n3 = bperm_f(i3, my_n);
            uint4 u0 = ((const uint4*)(xb + (size_t)s0 * 128))[fl];
            uint4 u1 = ((const uint4*)(xb + (size_t)s1 * 128))[fl];
            uint4 u2 = ((const uint4*)(xb + (size_t)s2 * 128))[fl];
            uint4 u3 = ((const uint4*)(xb + (size_t)s3 * 128))[fl];
            accA0.x = fmaf(bf_lo(u0.x), n0, accA0.x); accA0.y = fmaf(bf_hi(u0.x), n0, accA0.y);
            accA0.z = fmaf(bf_lo(u0.y), n0, accA0.z); accA0.w = fmaf(bf_hi(u0.y), n0, accA0.w);
            accB0.x = fmaf(bf_lo(u0.z), n0, accB0.x); accB0.y = fmaf(bf_hi(u0.z), n0, accB0.y);
            accB0.z = fmaf(bf_lo(u0.w), n0, accB0.z); accB0.w = fmaf(bf_hi(u0.w), n0, accB0.w);
            accA1.x = fmaf(bf_lo(u1.x), n1, accA1.x); accA1.y = fmaf(bf_hi(u1.x), n1, accA1.y);
            accA1.z = fmaf(bf_lo(u1.y), n1, accA1.z); accA1.w = fmaf(bf_hi(u1.y), n1, accA1.w);
            accB1.x = fmaf(bf_lo(u1.z), n1, accB1.x); accB1.y = fmaf(bf_hi(u1.z), n1, accB1.y);
            accB1.z = fmaf(bf_lo(u1.w), n1, accB1.z); accB1.w = fmaf(bf_hi(u1.w), n1, accB1.w);
            accA0.x = fmaf(bf_lo(u2.x), n2, accA0.x); accA0.y = fmaf(bf_hi(u2.x), n2, accA0.y);
            accA0.z = fmaf(bf_lo(u2.y), n2, accA0.z); accA0.w = fmaf(bf_hi(u2.y), n2, accA0.w);
            accB0.x = fmaf(bf_lo(u2.z), n2, accB0.x); accB0.y = fmaf(bf_hi(u2.z), n2, accB0.y);
            accB0.z = fmaf(bf_lo(u2.w), n2, accB0.z); accB0.w = fmaf(bf_hi(u2.w), n2, accB0.w);
            accA1.x = fmaf(bf_lo(u3.x), n3, accA1.x); accA1.y = fmaf(bf_hi(u3.x), n3, accA1.y);
            accA1.z = fmaf(bf_lo(u3.y), n3, accA1.z); accA1.w = fmaf(bf_hi(u3.y), n3, accA1.w);
            accB1.x = fmaf(bf_lo(u3.z), n3, accB1.x); accB1.y = fmaf(bf_hi(u3.z), n3, accB1.y);
            accB1.z = fmaf(bf_lo(u3.w), n3, accB1.z); accB1.w = fmaf(bf_hi(u3.w), n3, accB1.w);
        }
        for (; k + 4 <= cnt; k += 4) {        // full single group
            int i0 = k + quarter;
            int s0 = bperm_i(i0, my_e);
            float n0 = bperm_f(i0, my_n);
            uint4 u0 = ((const uint4*)(xb + (size_t)s0 * 128))[fl];
            accA0.x = fmaf(bf_lo(u0.x), n0, accA0.x); accA0.y = fmaf(bf_hi(u0.x), n0, accA0.y);
            accA0.z = fmaf(bf_lo(u0.y), n0, accA0.z); accA0.w = fmaf(bf_hi(u0.y), n0, accA0.w);
            accB0.x = fmaf(bf_lo(u0.z), n0, accB0.x); accB0.y = fmaf(bf_hi(u0.z), n0, accB0.y);
            accB0.z = fmaf(bf_lo(u0.w), n0, accB0.z); accB0.w = fmaf(bf_hi(u0.w), n0, accB0.w);
        }
        if (k < cnt) {                        // tail group: clamp idx, zero norm
            int ir = k + quarter;
            int i0 = min(ir, cm1);
            int s0 = bperm_i(i0, my_e);
            float n0 = bperm_f(i0, my_n);
            if (ir > cm1) n0 = 0.f;
            uint4 u0 = ((const uint4*)(xb + (size_t)s0 * 128))[fl];
            accA0.x = fmaf(bf_lo(u0.x), n0, accA0.x); accA0.y = fmaf(bf_hi(u0.x), n0, accA0.y);
            accA0.z = fmaf(bf_lo(u0.y), n0, accA0.z); accA0.w = fmaf(bf_hi(u0.y), n0, accA0.w);
            accB0.x = fmaf(bf_lo(u0.z), n0, accB0.x); accB0.y = fmaf(bf_hi(u0.z), n0, accB0.y);
            accB0.z = fmaf(bf_lo(u0.w), n0, accB0.z); accB0.w = fmaf(bf_hi(u0.w), n0, accB0.w);
        }
    }

    float4 sA4, sB4;
    sA4.x = accA0.x + accA1.x; sA4.y = accA0.y + accA1.y;
    sA4.z = accA0.z + accA1.z; sA4.w = accA0.w + accA1.w;
    sB4.x = accB0.x + accB1.x; sB4.y = accB0.y + accB1.y;
    sB4.z = accB0.z + accB1.z; sB4.w = accB0.w + accB1.w;
    sA4.x += __shfl_xor(sA4.x, 32, 64); sA4.y += __shfl_xor(sA4.y, 32, 64);
    sA4.z += __shfl_xor(sA4.z, 32, 64); sA4.w += __shfl_xor(sA4.w, 32, 64);
    sB4.x += __shfl_xor(sB4.x, 32, 64); sB4.y += __shfl_xor(sB4.y, 32, 64);
    sB4.z += __shfl_xor(sB4.z, 32, 64); sB4.w += __shfl_xor(sB4.w, 32, 64);
    sA4.x += __shfl_xor(sA4.x, 16, 64); sA4.y += __shfl_xor(sA4.y, 16, 64);
    sA4.z += __shfl_xor(sA4.z, 16, 64); sA4.w += __shfl_xor(sA4.w, 16, 64);
    sB4.x += __shfl_xor(sB4.x, 16, 64); sB4.y += __shfl_xor(sB4.y, 16, 64);
    sB4.z += __shfl_xor(sB4.z, 16, 64); sB4.w += __shfl_xor(sB4.w, 16, 64);

    if (quarter == 0) {
        float ni = norm_in[node];
        float no = norm_out[node];
        float4 bb0 = ((const float4*)b1)[2 * fl];
        float4 bb1 = ((const float4*)b1)[2 * fl + 1];
        float4 r0, r1;
        r0.x = fmaxf(fmaf(sA4.x, ni, bb0.x), 0.f) * no;
        r0.y = fmaxf(fmaf(sA4.y, ni, bb0.y), 0.f) * no;
        r0.z = fmaxf(fmaf(sA4.z, ni, bb0.z), 0.f) * no;
        r0.w = fmaxf(fmaf(sA4.w, ni, bb0.w), 0.f) * no;
        r1.x = fmaxf(fmaf(sB4.x, ni, bb1.x), 0.f) * no;
        r1.y = fmaxf(fmaf(sB4.y, ni, bb1.y), 0.f) * no;
        r1.z = fmaxf(fmaf(sB4.z, ni, bb1.z), 0.f) * no;
        r1.w = fmaxf(fmaf(sB4.w, ni, bb1.w), 0.f) * no;
        ((float4*)(out + (size_t)node * 128))[2 * fl]     = r0;
        ((float4*)(out + (size_t)node * 128))[2 * fl + 1] = r1;
    }
}

// ---------------- pull aggregation, 64 fp16 feats: 4 edges per VMEM inst ----------------
// quarter = lane>>4; each lane loads uint2 = 4 fp16 feats. Tail via clamp + 0-mask.
__global__ __launch_bounds__(256) void pull64_kernel(const unsigned* __restrict__ x,
                                                     const int* __restrict__ row_ptr,
                                                     const int* __restrict__ bsum,
                                                     const int* __restrict__ eidx,
                                                     const float* __restrict__ b2,
                                                     const float* __restrict__ norm_in,
                                                     float* __restrict__ out) {
    int node = blockIdx.x * 4 + (threadIdx.x >> 6);
    node = __builtin_amdgcn_readfirstlane(node);
    const int lane = threadIdx.x & 63;
    const int quarter = lane >> 4;
    const int fl = lane & 15;
    const int beg = __builtin_amdgcn_readfirstlane(row_ptr[node] + bsum[node >> 8]);
    const int end = __builtin_amdgcn_readfirstlane(row_ptr[node + 1] + bsum[(node + 1) >> 8]);

    float4 q0 = make_float4(0.f, 0.f, 0.f, 0.f);
    float4 q1 = make_float4(0.f, 0.f, 0.f, 0.f);

    for (int base = beg; base < end; base += 64) {
        const int cnt = min(64, end - base);
        const int cm1 = cnt - 1;
        int my_e = (lane < cnt) ? eidx[base + lane] : 0;
        int k = 0;
        for (; k + 16 <= cnt; k += 16) {
            int i0 = k + quarter, i1 = k + 4 + quarter, i2 = k + 8 + quarter, i3 = k + 12 + quarter;
            int s0 = bperm_i(i0, my_e);
            int s1 = bperm_i(i1, my_e);
            int s2 = bperm_i(i2, my_e);
            int s3 = bperm_i(i3, my_e);
            uint2 u0 = ((const uint2*)(x + (size_t)s0 * 32))[fl];
            uint2 u1 = ((const uint2*)(x + (size_t)s1 * 32))[fl];
            uint2 u2 = ((const uint2*)(x + (size_t)s2 * 32))[fl];
            uint2 u3 = ((const uint2*)(x + (size_t)s3 * 32))[fl];
            float2 v0a = unpack_f16x2(u0.x), v0b = unpack_f16x2(u0.y);
            float2 v1a = unpack_f16x2(u1.x), v1b = unpack_f16x2(u1.y);
            float2 v2a = unpack_f16x2(u2.x), v2b = unpack_f16x2(u2.y);
            float2 v3a = unpack_f16x2(u3.x), v3b = unpack_f16x2(u3.y);
            q0.x += v0a.x; q0.y += v0a.y; q0.z += v0b.x; q0.w += v0b.y;
            q1.x += v1a.x; q1.y += v1a.y; q1.z += v1b.x; q1.w += v1b.y;
            q0.x += v2a.x; q0.y += v2a.y; q0.z += v2b.x; q0.w += v2b.y;
            q1.x += v3a.x; q1.y += v3a.y; q1.z += v3b.x; q1.w += v3b.y;
        }
        for (; k + 4 <= cnt; k += 4) {
            int i0 = k + quarter;
            int s0 = bperm_i(i0, my_e);
            uint2 u0 = ((const uint2*)(x + (size_t)s0 * 32))[fl];
            float2 va = unpack_f16x2(u0.x), vb = unpack_f16x2(u0.y);
            q0.x += va.x; q0.y += va.y; q0.z += vb.x; q0.w += vb.y;
        }
        if (k < cnt) {
            int ir = k + quarter;
            int i0 = min(ir, cm1);
            int s0 = bperm_i(i0, my_e);
            float m = (ir > cm1) ? 0.f : 1.f;
            uint2 u0 = ((const uint2*)(x + (size_t)s0 * 32))[fl];
            float2 va = unpack_f16x2(u0.x), vb = unpack_f16x2(u0.y);
            q0.x = fmaf(va.x, m, q0.x); q0.y = fmaf(va.y, m, q0.y);
            q0.z = fmaf(vb.x, m, q0.z); q0.w = fmaf(vb.y, m, q0.w);
        }
    }

    float4 s4;
    s4.x = q0.x + q1.x; s4.y = q0.y + q1.y; s4.z = q0.z + q1.z; s4.w = q0.w + q1.w;
    s4.x += __shfl_xor(s4.x, 32, 64); s4.y += __shfl_xor(s4.y, 32, 64);
    s4.z += __shfl_xor(s4.z, 32, 64); s4.w += __shfl_xor(s4.w, 32, 64);
    s4.x += __shfl_xor(s4.x, 16, 64); s4.y += __shfl_xor(s4.y, 16, 64);
    s4.z += __shfl_xor(s4.z, 16, 64); s4.w += __shfl_xor(s4.w, 16, 64);

    if (quarter == 0) {
        float ni = norm_in[node];
        float4 bb = ((const float4*)b2)[fl];
        float4 r;
        r.x = fmaxf(fmaf(s4.x, ni, bb.x), 0.f);
        r.y = fmaxf(fmaf(s4.y, ni, bb.y), 0.f);
        r.z = fmaxf(fmaf(s4.z, ni, bb.z), 0.f);
        r.w = fmaxf(fmaf(s4.w, ni, bb.w), 0.f);
        ((float4*)(out + (size_t)node * 64))[fl] = r;
    }
}

extern "C" void kernel_launch(void* const* d_in, const int* in_sizes, int n_in,
                              void* d_out, int out_size, void* d_ws, size_t ws_size,
                              hipStream_t stream) {
    const float* h  = (const float*)d_in[0];
    const float* W1 = (const float*)d_in[1];
    const float* b1 = (const float*)d_in[2];
    const float* W2 = (const float*)d_in[3];
    const float* b2 = (const float*)d_in[4];
    const int* src  = (const int*)d_in[5];
    const int* dst  = (const int*)d_in[6];
    float* out = (float*)d_out;

    char* ws = (char*)d_ws;
    size_t off = 0;
    auto alloc = [&](size_t bytes) {
        void* p = ws + off;
        off = (off + bytes + 255) & ~(size_t)255;
        return p;
    };
    float* norm_out   = (float*)alloc(N_NODES * sizeof(float));
    float* norm_in    = (float*)alloc(N_NODES * sizeof(float));
    int* row_ptr      = (int*)alloc((N_NODES + 1) * sizeof(int));
    int* bsum         = (int*)alloc(NBS * sizeof(int));
    int* eidx         = (int*)alloc((size_t)N_EDGES * sizeof(int));                       // 3.2 MB
    unsigned short* t1 = (unsigned short*)alloc((size_t)N_NODES * 128 * sizeof(short));   // 12.8 MB bf16 (reused as fp16 t2)
    float* h1p        = (float*)alloc((size_t)N_NODES * 128 * sizeof(float));             // 25.6 MB

    // hist/prefix scratch aliases into h1p (dead until pull128 writes h1p):
    unsigned char* cntD = (unsigned char*)h1p;                    // 128 * 50000 = 6.4 MB
    unsigned char* cntS = cntD + (size_t)CHUNKS * 50000;          // 6.4 MB
    unsigned char* rp   = cntS + (size_t)CHUNKS * 50000;          // 0.8 MB
    unsigned short* t2h = t1;    // t1 dead after pull128; 50000*64*2 = 6.4 MB fits

    // degree/rank histograms (LDS atomics, no global atomics)
    hist_kernel<<<CHUNKS, 1024, 0, stream>>>(src, dst, cntD, cntS, rp);

    // t1 = bf16(h @ W1)
    gemmA_kernel<<<GEMMA_TILES, 256, 0, stream>>>(h, W1, t1);

    // per-node chunk prefix + norms + block scan -> partial row_ptr + bsum
    deg_scan_kernel<<<NBS, 256, 0, stream>>>(cntD, cntS, row_ptr, bsum, norm_out, norm_in);

    // scan of block sums (also writes row_ptr[N_NODES])
    scan2_kernel<<<1, 64, 0, stream>>>(bsum, row_ptr);

    // atomic-free CSR placement
    place_kernel<<<(N_EDGES + 255) / 256, 256, 0, stream>>>(src, dst, row_ptr, bsum, cntD, rp, eidx);

    // layer 1 pull (bf16 gather, 4 edges/inst, bpermute broadcast)
    pull128_kernel<<<N_NODES / 4, 256, 0, stream>>>(t1, row_ptr, bsum, eidx, b1,
                                                    norm_in, norm_out, h1p);

    // layer 2
    gemmB_kernel<<<(N_NODES + 31) / 32, 256, 0, stream>>>(h1p, W2, t2h);
    pull64_kernel<<<N_NODES / 4, 256, 0, stream>>>((const unsigned*)t2h, row_ptr, bsum, eidx,
                                                   b2, norm_in, out);
}